// Round 9
// baseline (1122.984 us; speedup 1.0000x reference)
//
#include <hip/hip_runtime.h>

// ---------------------------------------------------------------------------
// LoRA QKV: out_p = x @ (W_p + B_p @ A_p)^T  for p in {q,k,v}
// M = 8192, N = 4096 per proj (x3), K = 4096.
// Fold LoRA into weights (exact), bf16 convert (merged prep), fused 3-proj
// GEMM: 256x256 tile, 16x16x32 MFMA, 8 single-barrier phases with
// READ-AHEAD-1 + counted lgkmcnt (true T3/T4: LDS pipe overlaps MFMA pipe).
// ---------------------------------------------------------------------------

typedef __bf16 bf16x8 __attribute__((ext_vector_type(8)));
typedef float f32x4 __attribute__((ext_vector_type(4)));

#define GLL16(g, l)                                                        \
  __builtin_amdgcn_global_load_lds(                                        \
      (const __attribute__((address_space(1))) unsigned int*)(g),          \
      (__attribute__((address_space(3))) unsigned int*)(l), 16, 0, 0)

#define BAR()                                                              \
  {                                                                        \
    __builtin_amdgcn_sched_barrier(0);                                     \
    __builtin_amdgcn_s_barrier();                                          \
  }
// counted lgkm wait + sched fence (rule #18: stop MFMA hoisting past it)
#define WLGS(n)                                                            \
  {                                                                        \
    asm volatile("s_waitcnt lgkmcnt(" #n ")" ::: "memory");                \
    __builtin_amdgcn_sched_barrier(0);                                     \
  }
#define WVM(n) asm volatile("s_waitcnt vmcnt(" #n ")" ::: "memory")

#define LDV(p) (*reinterpret_cast<const bf16x8*>(p))

// read 4 A m-frags (one m-half), both k-substeps -> dst[2][4]  (8 reads)
#define RDA4(dst, base)                                                    \
  _Pragma("unroll") for (int mq = 0; mq < 4; ++mq) {                       \
    dst[0][mq] = LDV((base) + mq * 1024 + swk0);                           \
    dst[1][mq] = LDV((base) + mq * 1024 + swk1);                           \
  }
// read 2 B n-frags (n = N0..N0+1), both k-substeps -> dst[2][2]  (4 reads)
#define RDB2(dst, base, N0)                                                \
  _Pragma("unroll") for (int nq = 0; nq < 2; ++nq) {                       \
    dst[0][nq] = LDV((base) + ((N0) + nq) * 1024 + swk0);                  \
    dst[1][nq] = LDV((base) + ((N0) + nq) * 1024 + swk1);                  \
  }

// one C-quadrant x K=64: 16 MFMAs, 8 independent acc chains (len 2), T5
#define MFQ(AQ, BQ, MB, NB)                                                \
  {                                                                        \
    __builtin_amdgcn_s_setprio(1);                                         \
    _Pragma("unroll") for (int ks = 0; ks < 2; ++ks)                       \
        _Pragma("unroll") for (int mm = 0; mm < 4; ++mm)                   \
            _Pragma("unroll") for (int nn = 0; nn < 2; ++nn)               \
                acc[(MB) + mm][(NB) + nn] =                                \
                    __builtin_amdgcn_mfma_f32_16x16x32_bf16(               \
                        AQ[ks][mm], BQ[ks][nn], acc[(MB) + mm][(NB) + nn], \
                        0, 0, 0);                                          \
    __builtin_amdgcn_s_setprio(0);                                         \
  }

// stage one 16KB half-tile (2 loads/thread). h = 128-row half, ko = K elem.
#define STG_A(db, h, ko)                                                   \
  {                                                                        \
    GLL16(sa + (size_t)((h)*128) * 4096 + (ko),                            \
          (char*)smem + (db)*65536 + (h)*16384 + tid * 16);                \
    GLL16(sa + (size_t)((h)*128 + 64) * 4096 + (ko),                       \
          (char*)smem + (db)*65536 + (h)*16384 + 8192 + tid * 16);         \
  }
#define STG_B(db, h, ko)                                                   \
  {                                                                        \
    GLL16(sb + (size_t)((h)*128) * 4096 + (ko),                            \
          (char*)smem + (db)*65536 + 32768 + (h)*16384 + tid * 16);        \
    GLL16(sb + (size_t)((h)*128 + 64) * 4096 + (ko),                       \
          (char*)smem + (db)*65536 + 32768 + (h)*16384 + 8192 + tid * 16); \
  }

__device__ __forceinline__ unsigned int f2b(float f) {
  unsigned int u = __builtin_bit_cast(unsigned int, f);
  u += 0x7FFFu + ((u >> 16) & 1u);
  return u >> 16;
}

// ---------------------------------------------------------------------------
// Prep (single launch): blocks 0..8191 convert x -> bf16 (16 elems/thread);
// blocks 8192..32767 fold W' = W + B@A for proj 0..2 (8192 blocks each).
// ---------------------------------------------------------------------------
__global__ void prep_kernel(const float* __restrict__ x,
                            const float* __restrict__ w0,
                            const float* __restrict__ w1,
                            const float* __restrict__ w2,
                            const float* __restrict__ a0,
                            const float* __restrict__ b0,
                            const float* __restrict__ a1,
                            const float* __restrict__ b1,
                            const float* __restrict__ a2,
                            const float* __restrict__ b2,
                            unsigned short* __restrict__ xb,
                            unsigned short* __restrict__ wb) {
  const int bid = blockIdx.x;
  const int tid = threadIdx.x;
  if (bid < 8192) {
    long base = ((long)bid * 256 + tid) * 2;
    const float4* xp = reinterpret_cast<const float4*>(x) + base * 2;
#pragma unroll
    for (int j = 0; j < 2; ++j) {
      float4 v0 = xp[2 * j];
      float4 v1 = xp[2 * j + 1];
      uint4 o;
      o.x = f2b(v0.x) | (f2b(v0.y) << 16);
      o.y = f2b(v0.z) | (f2b(v0.w) << 16);
      o.z = f2b(v1.x) | (f2b(v1.y) << 16);
      o.w = f2b(v1.z) | (f2b(v1.w) << 16);
      reinterpret_cast<uint4*>(xb)[base + j] = o;
    }
  } else {
    const int fb = bid - 8192;
    const int proj = fb >> 13;  // 0..2
    const float* W = (proj == 0) ? w0 : ((proj == 1) ? w1 : w2);
    const float* Amat = (proj == 0) ? a0 : ((proj == 1) ? a1 : a2);
    const float* Bmat = (proj == 0) ? b0 : ((proj == 1) ? b1 : b2);
    unsigned short* Wo = wb + (size_t)proj * 16777216UL;
    int gi = (fb & 8191) * 256 + tid;
    int d0 = (gi & 511) * 8;
    int h = gi >> 9;
    const float4* wp =
        reinterpret_cast<const float4*>(W + (size_t)h * 4096 + d0);
    float4 w0v = wp[0], w1v = wp[1];
    float acc[8] = {w0v.x, w0v.y, w0v.z, w0v.w, w1v.x, w1v.y, w1v.z, w1v.w};
    const float* bh = Bmat + h * 16;
#pragma unroll
    for (int r = 0; r < 16; ++r) {
      float bv = bh[r];
      const float4* ap =
          reinterpret_cast<const float4*>(Amat + (size_t)r * 4096 + d0);
      float4 A0 = ap[0], A1 = ap[1];
      acc[0] += bv * A0.x; acc[1] += bv * A0.y;
      acc[2] += bv * A0.z; acc[3] += bv * A0.w;
      acc[4] += bv * A1.x; acc[5] += bv * A1.y;
      acc[6] += bv * A1.z; acc[7] += bv * A1.w;
    }
    uint4 o;
    o.x = f2b(acc[0]) | (f2b(acc[1]) << 16);
    o.y = f2b(acc[2]) | (f2b(acc[3]) << 16);
    o.z = f2b(acc[4]) | (f2b(acc[5]) << 16);
    o.w = f2b(acc[6]) | (f2b(acc[7]) << 16);
    reinterpret_cast<uint4*>(Wo)[gi] = o;
  }
}

// ---------------------------------------------------------------------------
// GEMM: 256x256 tile, mfma_f32_16x16x32_bf16 (r4 geometry/swizzle, measured
// 0 bank conflicts), restructured to 8 SINGLE-barrier phases with
// READ-AHEAD-1 and counted lgkmcnt.
//
// Phase k: { ds_reads for quadrant k+1 | stage | [vm] } BAR  WLG(n_k) MFMA_k
//   => a wave's MFMAs never wait on its same-phase reads; LDS-read burst of
//   phase k+1 executes concurrently with MFMA burst of phase k across waves.
// Quadrants per K-tile: q00(aLo,bLo) q01(aLo,bHi) q11(aHi,bHi) q10(aHi,bLo).
// Read issue: P8':q00(12) P1:bHi(4) P2:aHi(8) P3:- P4:q00buf1(12) P5:bHi(4)
//             P6:aHi(8) P7:- ; WLG counts = own-phase reads (4/8/0/12/...),
//   each wait covers reads issued one full phase earlier (near-zero stall).
// bLo is ping-ponged (bLoA=buf0, bLoB=buf1): P4/P8 write one while MFMA q10
//   consumes the other (static names, no runtime indexing).
// Stage map (every stage >=2 barrier-windows after region's last read-issue;
// drained tile's youngest load >=2 phases old):
//   P1: curD1.A1 | P3: T2.B0+B1, WVM(4) | P4: T2.A0 | P5: T2.A1
//   P7: T3.B0+B1, WVM(4) | P8: T3.A0     (T2=tile 2i+2, T3=tile 2i+3)
// Ledger: entering P1 outstanding=6 (T3'.B,A0); P1 +2 (A1) =8 = curD1.
//   P3: 8+4=12, WVM(4) drains curD1's 8 -> buf1 readable at P4.  [i=31: WVM(0)]
//   P7: 8+4=12, WVM(4) drains T2's 8 -> buf0-next readable at P8.
// ---------------------------------------------------------------------------
__global__ __launch_bounds__(512, 2) void gemm_kernel(
    const unsigned short* __restrict__ Xb,
    const unsigned short* __restrict__ Wb, float* __restrict__ out) {
  __shared__ unsigned short smem[65536];  // 128 KiB

  const int tid = threadIdx.x;
  const int lane = tid & 63;
  const int wid = tid >> 6;
  const int wm = wid >> 2;  // 0..1
  const int wn = wid & 3;   // 0..3

  int bid = blockIdx.x;                    // 1536 = 3 proj * 32 brow * 16 bcol
  int swz = (bid & 7) * 192 + (bid >> 3);  // bijective XCD swizzle
  int p = swz >> 9;
  int r = swz & 511;
  int brow = r >> 4;  // 0..31
  int bcol = r & 15;  // 0..15

  const unsigned short* GA = Xb + (size_t)brow * 256 * 4096;
  const unsigned short* GB =
      Wb + (size_t)p * 16777216UL + (size_t)bcol * 256 * 4096;

  // staging source, pre-swizzled (r4): LDS[r][s] holds global[r][s^(r&7)]
  const int srow = tid >> 3;
  const int sslot = (tid & 7) ^ (srow & 7);
  const unsigned short* sa = GA + (size_t)srow * 4096 + sslot * 8;
  const unsigned short* sb = GB + (size_t)srow * 4096 + sslot * 8;

  // fragment reads (r4): row = mt*16 + lrow; k-slot g=lane>>4, phys = lin^(r&7)
  const int lrow = lane & 15;
  const int g = lane >> 4;  // 0..3
  const int swk0 = (g ^ (lane & 7)) * 8;
  const int swk1 = ((4 + g) ^ (lane & 7)) * 8;
  const __bf16* sm = (const __bf16*)smem;
  const __bf16* arA0 = sm + wm * 8192 + lrow * 64;          // m-half 0 base
  const __bf16* arB0 =
      sm + 16384 + (wn >> 1) * 8192 + ((wn & 1) * 64 + lrow) * 64;
  const __bf16* arA1 = arA0 + 32768;
  const __bf16* arB1 = arB0 + 32768;

  f32x4 acc[8][4];
#pragma unroll
  for (int m = 0; m < 8; ++m)
#pragma unroll
    for (int n = 0; n < 4; ++n) acc[m][n] = {0.f, 0.f, 0.f, 0.f};

  // prologue: T0 full -> buf0, T1 full -> buf1
  STG_B(0, 0, 0); STG_B(0, 1, 0); STG_A(0, 0, 0); STG_A(0, 1, 0);
  STG_B(1, 0, 64); STG_B(1, 1, 64); STG_A(1, 0, 64); STG_A(1, 1, 64);
  WVM(8);  // T0 landed; T1's 8 in flight
  BAR();

  bf16x8 aLo[2][4], aHi[2][4], bHi[2][2], bLoA[2][2], bLoB[2][2];

  // pre-read q00(buf0) for P1's MFMA
  RDA4(aLo, arA0);
  RDB2(bLoA, arB0, 0);

  for (int i = 0; i < 32; ++i) {
    const bool st = (i < 31);
    const bool sp = (i > 0);
    const size_t koD1 = (size_t)(2 * i + 1) * 64;
    const size_t koN0 = (size_t)(2 * i + 2) * 64;
    const size_t koN1 = (size_t)(2 * i + 3) * 64;

    // P1: reads bHi(buf0); stage curD1.A1; MFMA q00(buf0)
    RDB2(bHi, arB0, 2);
    if (sp) STG_A(1, 1, koD1);
    BAR();
    WLGS(4);
    MFQ(aLo, bLoA, 0, 0);
    // P2: reads aHi(buf0); MFMA q01(buf0)
    RDA4(aHi, arA0 + 4096);
    BAR();
    WLGS(8);
    MFQ(aLo, bHi, 0, 2);
    // P3: stage T2.B0+B1; drain curD1 (buf1) for P4's reads; MFMA q11(buf0)
    if (st) {
      STG_B(0, 0, koN0);
      STG_B(0, 1, koN0);
      WVM(4);
    } else {
      WVM(0);
    }
    BAR();
    WLGS(0);
    MFQ(aHi, bHi, 4, 2);
    // P4: reads q00(buf1) -> aLo,bLoB; stage T2.A0; MFMA q10(buf0)
    RDA4(aLo, arA1);
    RDB2(bLoB, arB1, 0);
    if (st) STG_A(0, 0, koN0);
    BAR();
    WLGS(12);
    MFQ(aHi, bLoA, 4, 0);
    // P5: reads bHi(buf1); stage T2.A1; MFMA q00(buf1)
    RDB2(bHi, arB1, 2);
    if (st) STG_A(0, 1, koN0);
    BAR();
    WLGS(4);
    MFQ(aLo, bLoB, 0, 0);
    // P6: reads aHi(buf1); MFMA q01(buf1)
    RDA4(aHi, arA1 + 4096);
    BAR();
    WLGS(8);
    MFQ(aLo, bHi, 0, 2);
    // P7: stage T3.B0+B1; drain T2 (buf0-next) for P8's reads; MFMA q11(buf1)
    if (st) {
      STG_B(1, 0, koN1);
      STG_B(1, 1, koN1);
      WVM(4);
    }
    BAR();
    WLGS(0);
    MFQ(aHi, bHi, 4, 2);
    // P8: reads q00(next buf0) -> aLo,bLoA; stage T3.A0; MFMA q10(buf1)
    if (st) {
      RDA4(aLo, arA0);
      RDB2(bLoA, arB0, 0);
      STG_A(1, 0, koN1);
    }
    BAR();
    if (st) {
      WLGS(12);
    } else {
      WLGS(0);
    }
    MFQ(aHi, bLoB, 4, 0);
  }

  // epilogue: C/D layout col = lane&15, row = (lane>>4)*4 + q  [m89]
  float* Cp = out + (size_t)p * 33554432UL +
              ((size_t)(brow * 256 + wm * 128 + g * 4)) * 4096 +
              (bcol * 256 + wn * 64 + lrow);
#pragma unroll
  for (int m = 0; m < 8; ++m)
#pragma unroll
    for (int q = 0; q < 4; ++q) {
      float* rp = Cp + (size_t)(m * 16 + q) * 4096;
#pragma unroll
      for (int n = 0; n < 4; ++n) rp[n * 16] = acc[m][n][q];
    }
}

// ---------------------------------------------------------------------------
extern "C" void kernel_launch(void* const* d_in, const int* in_sizes, int n_in,
                              void* d_out, int out_size, void* d_ws,
                              size_t ws_size, hipStream_t stream) {
  const float* x = (const float*)d_in[0];
  const float* wq = (const float*)d_in[1];
  const float* wk = (const float*)d_in[2];
  const float* wv = (const float*)d_in[3];
  const float* qa = (const float*)d_in[4];
  const float* qb = (const float*)d_in[5];
  const float* ka = (const float*)d_in[6];
  const float* kb = (const float*)d_in[7];
  const float* va = (const float*)d_in[8];
  const float* vb = (const float*)d_in[9];

  unsigned short* xb = (unsigned short*)d_ws;  // 67 MB
  unsigned short* wb = xb + 8192UL * 4096UL;   // 100 MB

  prep_kernel<<<32768, 256, 0, stream>>>(x, wq, wk, wv, qa, qb, ka, kb, va,
                                         vb, xb, wb);
  gemm_kernel<<<1536, 512, 0, stream>>>(xb, wb, (float*)d_out);
}

// Round 10
// 901.150 us; speedup vs baseline: 1.2462x; 1.2462x over previous
//
#include <hip/hip_runtime.h>

// ---------------------------------------------------------------------------
// LoRA QKV: out_p = x @ (W_p + B_p @ A_p)^T  for p in {q,k,v}
// M = 8192, N = 4096 per proj (x3), K = 4096.
// Fold LoRA into weights (exact), bf16 convert (one merged prep kernel),
// fused 3-proj GEMM: m201 256x256 8-phase half-tile schedule, 16x16x32 MFMA.
// This round: recombination of the two best-measured components (R3-proposal
// GEMM ~710us + merged prep ~165us) after r9's read-ahead spill regression.
// ---------------------------------------------------------------------------

typedef __bf16 bf16x8 __attribute__((ext_vector_type(8)));
typedef float f32x4 __attribute__((ext_vector_type(4)));

#define GLL16(g, l)                                                        \
  __builtin_amdgcn_global_load_lds(                                        \
      (const __attribute__((address_space(1))) unsigned int*)(g),          \
      (__attribute__((address_space(3))) unsigned int*)(l), 16, 0, 0)

#define BAR()                                                              \
  {                                                                        \
    __builtin_amdgcn_sched_barrier(0);                                     \
    __builtin_amdgcn_s_barrier();                                          \
  }
#define WLG(n) asm volatile("s_waitcnt lgkmcnt(" #n ")" ::: "memory")
#define WVM(n) asm volatile("s_waitcnt vmcnt(" #n ")" ::: "memory")

#define LDV(p) (*reinterpret_cast<const bf16x8*>(p))

// read 4 A-frags (m = M0..M0+3), both k-substeps, into dst[2][4]
#define RDA(dst, base, M0)                                                 \
  _Pragma("unroll") for (int mm = 0; mm < 4; ++mm) {                       \
    dst[0][mm] = LDV((base) + ((M0) + mm) * 1024 + swk0);                  \
    dst[1][mm] = LDV((base) + ((M0) + mm) * 1024 + swk1);                  \
  }
// read 2 B-frags (n = N0..N0+1), both k-substeps, into dst[2][2]
#define RDB(dst, base, N0)                                                 \
  _Pragma("unroll") for (int nn = 0; nn < 2; ++nn) {                       \
    dst[0][nn] = LDV((base) + ((N0) + nn) * 1024 + swk0);                  \
    dst[1][nn] = LDV((base) + ((N0) + nn) * 1024 + swk1);                  \
  }

// one C-quadrant x K=64: 16 MFMAs, ks outer => 8 independent chains (len 2)
#define MFQ(AQ, BQ, MB, NB)                                                \
  {                                                                        \
    __builtin_amdgcn_s_setprio(1);                                         \
    _Pragma("unroll") for (int ks = 0; ks < 2; ++ks)                       \
        _Pragma("unroll") for (int mm = 0; mm < 4; ++mm)                   \
            _Pragma("unroll") for (int nn = 0; nn < 2; ++nn)               \
                acc[(MB) + mm][(NB) + nn] =                                \
                    __builtin_amdgcn_mfma_f32_16x16x32_bf16(               \
                        AQ[ks][mm], BQ[ks][nn], acc[(MB) + mm][(NB) + nn], \
                        0, 0, 0);                                          \
    __builtin_amdgcn_s_setprio(0);                                         \
  }

// stage one 16KB half-tile (2 loads/thread). h = 128-row half, ko = K elem.
#define STG_A(db, h, ko)                                                   \
  {                                                                        \
    GLL16(sa + (size_t)((h)*128) * 4096 + (ko),                            \
          (char*)smem + (db)*65536 + (h)*16384 + tid * 16);                \
    GLL16(sa + (size_t)((h)*128 + 64) * 4096 + (ko),                       \
          (char*)smem + (db)*65536 + (h)*16384 + 8192 + tid * 16);         \
  }
#define STG_B(db, h, ko)                                                   \
  {                                                                        \
    GLL16(sb + (size_t)((h)*128) * 4096 + (ko),                            \
          (char*)smem + (db)*65536 + 32768 + (h)*16384 + tid * 16);        \
    GLL16(sb + (size_t)((h)*128 + 64) * 4096 + (ko),                       \
          (char*)smem + (db)*65536 + 32768 + (h)*16384 + 8192 + tid * 16); \
  }

__device__ __forceinline__ unsigned int f2b(float f) {
  unsigned int u = __builtin_bit_cast(unsigned int, f);
  u += 0x7FFFu + ((u >> 16) & 1u);
  return u >> 16;
}

// ---------------------------------------------------------------------------
// Prep (single launch; measured r6): blocks 0..8191 convert x -> bf16
// (16 elems/thread); blocks 8192..32767 fold W' = W + B@A (proj 0..2).
// ---------------------------------------------------------------------------
__global__ void prep_kernel(const float* __restrict__ x,
                            const float* __restrict__ w0,
                            const float* __restrict__ w1,
                            const float* __restrict__ w2,
                            const float* __restrict__ a0,
                            const float* __restrict__ b0,
                            const float* __restrict__ a1,
                            const float* __restrict__ b1,
                            const float* __restrict__ a2,
                            const float* __restrict__ b2,
                            unsigned short* __restrict__ xb,
                            unsigned short* __restrict__ wb) {
  const int bid = blockIdx.x;
  const int tid = threadIdx.x;
  if (bid < 8192) {
    long base = ((long)bid * 256 + tid) * 2;
    const float4* xp = reinterpret_cast<const float4*>(x) + base * 2;
#pragma unroll
    for (int j = 0; j < 2; ++j) {
      float4 v0 = xp[2 * j];
      float4 v1 = xp[2 * j + 1];
      uint4 o;
      o.x = f2b(v0.x) | (f2b(v0.y) << 16);
      o.y = f2b(v0.z) | (f2b(v0.w) << 16);
      o.z = f2b(v1.x) | (f2b(v1.y) << 16);
      o.w = f2b(v1.z) | (f2b(v1.w) << 16);
      reinterpret_cast<uint4*>(xb)[base + j] = o;
    }
  } else {
    const int fb = bid - 8192;
    const int proj = fb >> 13;  // 0..2
    const float* W = (proj == 0) ? w0 : ((proj == 1) ? w1 : w2);
    const float* Amat = (proj == 0) ? a0 : ((proj == 1) ? a1 : a2);
    const float* Bmat = (proj == 0) ? b0 : ((proj == 1) ? b1 : b2);
    unsigned short* Wo = wb + (size_t)proj * 16777216UL;
    int gi = (fb & 8191) * 256 + tid;
    int d0 = (gi & 511) * 8;
    int h = gi >> 9;
    const float4* wp =
        reinterpret_cast<const float4*>(W + (size_t)h * 4096 + d0);
    float4 w0v = wp[0], w1v = wp[1];
    float acc[8] = {w0v.x, w0v.y, w0v.z, w0v.w, w1v.x, w1v.y, w1v.z, w1v.w};
    const float* bh = Bmat + h * 16;
#pragma unroll
    for (int r = 0; r < 16; ++r) {
      float bv = bh[r];
      const float4* ap =
          reinterpret_cast<const float4*>(Amat + (size_t)r * 4096 + d0);
      float4 A0 = ap[0], A1 = ap[1];
      acc[0] += bv * A0.x; acc[1] += bv * A0.y;
      acc[2] += bv * A0.z; acc[3] += bv * A0.w;
      acc[4] += bv * A1.x; acc[5] += bv * A1.y;
      acc[6] += bv * A1.z; acc[7] += bv * A1.w;
    }
    uint4 o;
    o.x = f2b(acc[0]) | (f2b(acc[1]) << 16);
    o.y = f2b(acc[2]) | (f2b(acc[3]) << 16);
    o.z = f2b(acc[4]) | (f2b(acc[5]) << 16);
    o.w = f2b(acc[6]) | (f2b(acc[7]) << 16);
    reinterpret_cast<uint4*>(Wo)[gi] = o;
  }
}

// ---------------------------------------------------------------------------
// GEMM: 256x256-tile 8-phase (m201 schedule, measured ~710us / 55% MfmaUtil).
//   C[M, N*3] = Xb[M,K] @ Wb[3][N,K]^T
// 512 threads = 8 waves (2M x 4N), wave tile 128x64. BK=64 (2 x K32).
// LDS 128 KiB = 2 dbuf x { A: 2 x 16KB row-halves | B: 2 x 16KB }.
// 16B-slot XOR swizzle (phys slot s of row r holds global slot s^(r&7));
// applied on global SOURCE (global_load_lds writes linearly) + read addr.
// Phase = { quadrant ds_reads (12/4/8/0) | 1 half-tile stage } -> barrier ->
// lgkmcnt(0) -> setprio(1) 16 MFMA setprio(0) -> barrier.
// Stage map (vmcnt(6)@P4/P8 ledger, depth-3):
//   P1: D1cur.A1 | P2: N0.B0 | P3: N0.B1 | P4: N0.A0 +vm(6)
//   P5: N0.A1    | P6: N1.B0 | P7: N1.B1 | P8: N1.A0 +vm(6)
// ---------------------------------------------------------------------------
__global__ __launch_bounds__(512, 2) void gemm_kernel(
    const unsigned short* __restrict__ Xb,
    const unsigned short* __restrict__ Wb, float* __restrict__ out) {
  __shared__ unsigned short smem[65536];  // 128 KiB

  const int tid = threadIdx.x;
  const int lane = tid & 63;
  const int wid = tid >> 6;
  const int wm = wid >> 2;  // 0..1
  const int wn = wid & 3;   // 0..3

  int bid = blockIdx.x;                    // 1536 = 3 proj * 32 brow * 16 bcol
  int swz = (bid & 7) * 192 + (bid >> 3);  // bijective XCD swizzle
  int p = swz >> 9;
  int r = swz & 511;
  int brow = r >> 4;  // 0..31
  int bcol = r & 15;  // 0..15

  const unsigned short* GA = Xb + (size_t)brow * 256 * 4096;
  const unsigned short* GB =
      Wb + (size_t)p * 16777216UL + (size_t)bcol * 256 * 4096;

  // staging source, pre-swizzled so LDS[r][s] holds global[r][s^(r&7)]
  const int srow = tid >> 3;
  const int sslot = (tid & 7) ^ (srow & 7);
  const unsigned short* sa = GA + (size_t)srow * 4096 + sslot * 8;
  const unsigned short* sb = GB + (size_t)srow * 4096 + sslot * 8;

  // fragment-read bases (element units), swizzled k-slot offsets
  const int lrow = lane & 15;
  const int g = lane >> 4;  // 0..3
  const int swk0 = (g ^ (lane & 7)) * 8;
  const int swk1 = ((4 + g) ^ (lane & 7)) * 8;
  const __bf16* sm = (const __bf16*)smem;
  const __bf16* arA0 = sm + wm * 8192 + lrow * 64;
  const __bf16* arB0 =
      sm + 16384 + (wn >> 1) * 8192 + ((wn & 1) * 64 + lrow) * 64;
  const __bf16* arA1 = arA0 + 32768;
  const __bf16* arB1 = arB0 + 32768;

  f32x4 acc[8][4];
#pragma unroll
  for (int m = 0; m < 8; ++m)
#pragma unroll
    for (int n = 0; n < 4; ++n) acc[m][n] = {0.f, 0.f, 0.f, 0.f};

  // prologue (ledger order B0,B1,A0,A1):
  STG_B(0, 0, 0); STG_B(0, 1, 0); STG_A(0, 0, 0); STG_A(0, 1, 0);
  WVM(4);
  STG_B(1, 0, 64); STG_B(1, 1, 64); STG_A(1, 0, 64);
  WVM(6);  // tile0 complete; 6 of tile1 in flight
  BAR();

  bf16x8 aLo[2][4], aHi[2][4], bLo[2][2], bHi[2][2];

  for (int i = 0; i < 32; ++i) {
    const bool st = (i < 31);
    const size_t koD1 = (size_t)(2 * i + 1) * 64;
    const size_t koN0 = (size_t)(2 * i + 2) * 64;
    const size_t koN1 = (size_t)(2 * i + 3) * 64;

    // ================= D0 (tile 2i) =================
    // P1: q00 reads (12); finish current D1 (A1)
    RDA(aLo, arA0, 0);
    RDB(bLo, arB0, 0);
    STG_A(1, 1, koD1);
    WLG(8);
    BAR();
    WLG(0);
    MFQ(aLo, bLo, 0, 0);
    BAR();
    // P2: q01 reads B n2-3 (4); stage N0.B0
    RDB(bHi, arB0, 2);
    if (st) STG_B(0, 0, koN0);
    BAR();
    WLG(0);
    MFQ(aLo, bHi, 0, 2);
    BAR();
    // P3: q11 reads A m4-7 (8); stage N0.B1
    RDA(aHi, arA0, 4);
    if (st) STG_B(0, 1, koN0);
    BAR();
    WLG(0);
    MFQ(aHi, bHi, 4, 2);
    BAR();
    // P4: q10 (0 reads); stage N0.A0; counted vmcnt -> D1 fully landed
    if (st) {
      STG_A(0, 0, koN0);
      WVM(6);
    } else {
      WVM(0);
    }
    BAR();
    MFQ(aHi, bLo, 4, 0);
    BAR();

    // ================= D1 (tile 2i+1) =================
    // P5: q00 reads (12); stage N0.A1
    RDA(aLo, arA1, 0);
    RDB(bLo, arB1, 0);
    if (st) STG_A(0, 1, koN0);
    WLG(8);
    BAR();
    WLG(0);
    MFQ(aLo, bLo, 0, 0);
    BAR();
    // P6: q01; stage N1.B0
    RDB(bHi, arB1, 2);
    if (st) STG_B(1, 0, koN1);
    BAR();
    WLG(0);
    MFQ(aLo, bHi, 0, 2);
    BAR();
    // P7: q11; stage N1.B1
    RDA(aHi, arA1, 4);
    if (st) STG_B(1, 1, koN1);
    BAR();
    WLG(0);
    MFQ(aHi, bHi, 4, 2);
    BAR();
    // P8: q10; stage N1.A0; counted vmcnt -> N0 fully landed
    if (st) {
      STG_A(1, 0, koN1);
      WVM(6);
    }
    BAR();
    MFQ(aHi, bLo, 4, 0);
    BAR();
  }

  // epilogue: C/D layout col = lane&15, row = (lane>>4)*4 + q
  float* Cp = out + (size_t)p * 33554432UL +
              ((size_t)(brow * 256 + wm * 128 + g * 4)) * 4096 +
              (bcol * 256 + wn * 64 + lrow);
#pragma unroll
  for (int m = 0; m < 8; ++m)
#pragma unroll
    for (int q = 0; q < 4; ++q) {
      float* rp = Cp + (size_t)(m * 16 + q) * 4096;
#pragma unroll
      for (int n = 0; n < 4; ++n) rp[n * 16] = acc[m][n][q];
    }
}

// ---------------------------------------------------------------------------
extern "C" void kernel_launch(void* const* d_in, const int* in_sizes, int n_in,
                              void* d_out, int out_size, void* d_ws,
                              size_t ws_size, hipStream_t stream) {
  const float* x = (const float*)d_in[0];
  const float* wq = (const float*)d_in[1];
  const float* wk = (const float*)d_in[2];
  const float* wv = (const float*)d_in[3];
  const float* qa = (const float*)d_in[4];
  const float* qb = (const float*)d_in[5];
  const float* ka = (const float*)d_in[6];
  const float* kb = (const float*)d_in[7];
  const float* va = (const float*)d_in[8];
  const float* vb = (const float*)d_in[9];

  unsigned short* xb = (unsigned short*)d_ws;  // 67 MB
  unsigned short* wb = xb + 8192UL * 4096UL;   // 100 MB

  prep_kernel<<<32768, 256, 0, stream>>>(x, wq, wk, wv, qa, qb, ka, kb, va,
                                         vb, xb, wb);
  gemm_kernel<<<1536, 512, 0, stream>>>(xb, wb, (float*)d_out);
}